// Round 12
// baseline (354.787 us; speedup 1.0000x reference)
//
#include <hip/hip_runtime.h>
#include <hip/hip_bf16.h>
#include <stdint.h>

// GWNN: out = L2(relu(L1(x))),  L(x) = W_wav · diag(f) · W_inv · (x·W)
// R12 = R11 (BM=128, split-K x4, 1 block/CU, NBUF ring, 1 barrier + counted
// vmcnt per step) + symmetric fused bf16-A copy:
//   G1/G2 (fp32 A) additionally store each wave's OWN cvt'd bf16 A fragments
//   (4 x 16B/lane/step, 64B segments) to WI16/WA16 in ws.
//   G3/G4 read bf16 A (ABF path): 16KB A tile, TSZ=32KB, NBUF=4, depth 3 ->
//   HBM term halved for the last two big GEMMs.
// Exact in-order vmcnt ladders: fp32+copy 12/16/20.../8 ; bf16 16.../8/0.
// Fallback to pure R11 (no copy) if ws_size too small.

typedef __attribute__((ext_vector_type(4))) float f32x4;
typedef __attribute__((ext_vector_type(8))) short s16x8;
typedef __attribute__((ext_vector_type(4))) short s16x4;

#define DEVI static __device__ __forceinline__

DEVI short bf1(float x){ __bf16 h = (__bf16)x; return __builtin_bit_cast(short, h); }

DEVI s16x8 cvt8(f32x4 lo, f32x4 hi){
  s16x8 r;
#pragma unroll
  for (int i = 0; i < 4; ++i){ r[i] = bf1(lo[i]); r[4+i] = bf1(hi[i]); }
  return r;
}

DEVI void glds16(const void* g, void* l){
  __builtin_amdgcn_global_load_lds((const __attribute__((address_space(1))) void*)g,
                                   (__attribute__((address_space(3))) void*)l, 16, 0, 0);
}

template<int N> DEVI void waitvm(){
  if constexpr (N == 0)       asm volatile("s_waitcnt vmcnt(0)"  ::: "memory");
  else if constexpr (N == 5)  asm volatile("s_waitcnt vmcnt(5)"  ::: "memory");
  else if constexpr (N == 6)  asm volatile("s_waitcnt vmcnt(6)"  ::: "memory");
  else if constexpr (N == 8)  asm volatile("s_waitcnt vmcnt(8)"  ::: "memory");
  else if constexpr (N == 12) asm volatile("s_waitcnt vmcnt(12)" ::: "memory");
  else if constexpr (N == 16) asm volatile("s_waitcnt vmcnt(16)" ::: "memory");
  else if constexpr (N == 20) asm volatile("s_waitcnt vmcnt(20)" ::: "memory");
}

// ============================================================================
// Big GEMM, BM=128, split-K x4: P[kq][M][128] = A @ Bt^T  (f32 partials).
// ABF=0: A fp32 (cvt at LDS read). WCOPY: store bf16 A fragments to Acp[M][K].
// ABF=1: A bf16 row-major (the copy), WCOPY must be false.
// ============================================================================
template<bool ABF, bool WCOPY>
__global__ __launch_bounds__(256, 1) void gemm_big(
    const void* __restrict__ Ap, const short* __restrict__ Btp,
    float* __restrict__ Pp, short* __restrict__ Acp, int K, int M)
{
  constexpr int BM = 128, BK = 64;
  constexpr int ASZ = ABF ? BM*BK*2 : BM*BK*4;   // 16 / 32 KB
  constexpr int BSZ = 128*BK*2;                   // 16 KB
  constexpr int TSZ = ASZ + BSZ;                  // 32 / 48 KB
  constexpr int NBUF = ABF ? 4 : 3;               // 128 / 144 KB
  constexpr int PRE  = ABF ? 3 : 2;
  __shared__ uint8_t lds[NBUF*TSZ];

  const int tid  = threadIdx.x;
  const int lane = tid & 63;
  const int wv   = tid >> 6;
  const int la   = lane & 15;
  const int g4   = lane >> 4;
  const int m0   = blockIdx.x * BM;
  const int kq   = blockIdx.y;
  const int K4   = K >> 2;
  const int kb   = kq * K4;

  // ---- A staging addresses (wave w stages its OWN rows 32w..32w+31)
  const float* gAf = nullptr; const short* gAh = nullptr;
  int aoffg[8];   // per-instruction global offsets (elements)
  if constexpr (!ABF){
    gAf = (const float*)Ap + (size_t)m0*K + kb;
#pragma unroll
    for (int j = 0; j < 8; ++j){
      const int rl = (wv<<5) + (j<<2) + (lane>>4);       // 4 rows / instr
      aoffg[j] = rl*K + (((lane&15) ^ (rl&15))<<2);
    }
  } else {
    gAh = (const short*)Ap + (size_t)m0*K + kb;
#pragma unroll
    for (int j = 0; j < 4; ++j){
      const int rl = (wv<<5) + (j<<3) + (lane>>3);       // 8 rows / instr
      aoffg[j] = rl*K + (((lane&7) ^ (rl&7))<<3);
    }
  }

  // ---- B staging (proven): wave w stages B rows 32w..32w+31, pre-swizzled
  const int nb0 = (wv<<5) + (lane>>3);
  const short* gB0 = Btp + (size_t)(nb0    )*K + kb + (((lane&7)^(nb0&7))<<3);
  const short* gB1 = Btp + (size_t)(nb0+ 8 )*K + kb + (((lane&7)^(nb0&7))<<3);
  const short* gB2 = Btp + (size_t)(nb0+16 )*K + kb + (((lane&7)^(nb0&7))<<3);
  const short* gB3 = Btp + (size_t)(nb0+24 )*K + kb + (((lane&7)^(nb0&7))<<3);

  // ---- fragment LDS byte offsets (XOR-swizzled reads), wave-private A rows
  int aoff[2][2][2];   // [mi][kf][part]
#pragma unroll
  for (int mi = 0; mi < 2; ++mi){
    const int r = (wv<<5) + mi*16 + la;
#pragma unroll
    for (int kf = 0; kf < 2; ++kf){
      if constexpr (!ABF){
        const int v0 = kf*8 + (g4<<1);
        aoff[mi][kf][0] = r*256 + (((v0  )^(r&15))<<4);
        aoff[mi][kf][1] = r*256 + (((v0+1)^(r&15))<<4);
      } else {
        const int u = kf*4 + g4;
        aoff[mi][kf][0] = r*128 + ((u^(r&7))<<4);
        aoff[mi][kf][1] = 0;
      }
    }
  }
  int boff[8][2];      // [ni][kf]
#pragma unroll
  for (int ni = 0; ni < 8; ++ni){
    const int n = ni*16 + la;
#pragma unroll
    for (int kf = 0; kf < 2; ++kf){
      const int u = kf*4 + g4;
      boff[ni][kf] = n*128 + ((u^(n&7))<<4);
    }
  }

  // ---- bf16-copy store base (WCOPY): row (m0 + 32w + la), col base g4*8
  short* Acw = nullptr;
  if constexpr (WCOPY)
    Acw = Acp + (size_t)(m0 + (wv<<5) + la)*K + kb + (g4<<3);

  f32x4 acc[2][8] = {};

  int kk = 0;     // staging k advance (elements)
  int kc = 0;     // compute/copy k advance (elements)
  uint8_t* const lend = lds + NBUF*TSZ;
  uint8_t* bs = lds;
  uint8_t* bc = lds;

  auto STAGE = [&](){
    uint8_t* Ab = bs;
    uint8_t* Bb = bs + ASZ;
    if constexpr (!ABF){
#pragma unroll
      for (int j = 0; j < 8; ++j)
        glds16(gAf + aoffg[j] + kk, Ab + (wv<<13) + (j<<10));
    } else {
#pragma unroll
      for (int j = 0; j < 4; ++j)
        glds16(gAh + aoffg[j] + kk, Ab + (wv<<12) + (j<<10));
    }
    kk += BK;
    glds16(gB0, Bb + (wv<<12));
    glds16(gB1, Bb + (wv<<12) + 1024);
    glds16(gB2, Bb + (wv<<12) + 2048);
    glds16(gB3, Bb + (wv<<12) + 3072);
    gB0 += BK; gB1 += BK; gB2 += BK; gB3 += BK;
    bs += TSZ; if (bs == lend) bs = lds;
  };

  auto COMPUTE = [&](){
    const uint8_t* Ab = bc;
    const uint8_t* Bb = bc + ASZ;
#pragma unroll
    for (int kf = 0; kf < 2; ++kf){
      s16x8 a0, a1;
      if constexpr (!ABF){
        a0 = cvt8(*(const f32x4*)(Ab + aoff[0][kf][0]),
                  *(const f32x4*)(Ab + aoff[0][kf][1]));
        a1 = cvt8(*(const f32x4*)(Ab + aoff[1][kf][0]),
                  *(const f32x4*)(Ab + aoff[1][kf][1]));
        if constexpr (WCOPY){
          *(s16x8*)(Acw + kc + kf*32)            = a0;   // rows 32w+la
          *(s16x8*)(Acw + (size_t)16*K + kc + kf*32) = a1; // rows +16
        }
      } else {
        a0 = *(const s16x8*)(Ab + aoff[0][kf][0]);
        a1 = *(const s16x8*)(Ab + aoff[1][kf][0]);
      }
#pragma unroll
      for (int ni = 0; ni < 8; ++ni){
        s16x8 b = *(const s16x8*)(Bb + boff[ni][kf]);
        acc[0][ni] = __builtin_amdgcn_mfma_f32_16x16x32_bf16(a0, b, acc[0][ni], 0, 0, 0);
        acc[1][ni] = __builtin_amdgcn_mfma_f32_16x16x32_bf16(a1, b, acc[1][ni], 0, 0, 0);
      }
    }
    kc += BK;
    bc += TSZ; if (bc == lend) bc = lds;
  };

  const int ns = K4 >> 6;                    // 32 steps
  for (int s = 0; s < PRE && s < ns; ++s) STAGE();

  for (int t = 0; t < ns; ++t){
    // exact in-order vmcnt ladders (stage t must be complete)
    if constexpr (ABF){
      if (t <= ns - 3)      waitvm<16>();    // t+1, t+2 in flight (8 ops each)
      else if (t == ns - 2) waitvm<8>();
      else                  waitvm<0>();
    } else if constexpr (WCOPY){
      if (t == 0)           waitvm<12>();    // stage1 in flight
      else if (t == 1)      waitvm<16>();    // stage2 + S0
      else if (t <= ns - 2) waitvm<20>();    // S(t-2) + stage(t+1) + S(t-1)
      else                  waitvm<8>();     // S(ns-3) + S(ns-2)
    } else {
      if (t < ns - 1) waitvm<12>(); else waitvm<0>();
    }
    __builtin_amdgcn_s_barrier();
    asm volatile("" ::: "memory");
    if (t + PRE < ns) STAGE();
    COMPUTE();
    asm volatile("" ::: "memory");
  }

  // ---- partial epilogue: f32 P[kq][M][128]
  float* P = Pp + (size_t)kq * M * 128;
  const int rbase = m0 + (wv<<5) + (g4<<2);
#pragma unroll
  for (int mi = 0; mi < 2; ++mi)
#pragma unroll
    for (int ni = 0; ni < 8; ++ni)
#pragma unroll
      for (int r = 0; r < 4; ++r)
        P[(size_t)(rbase + mi*16 + r)*128 + ni*16 + la] = acc[mi][ni][r];
}

// ============================================================================
// Small K=128 GEMM (proven): out = bf16 transposed [128][M].
// ============================================================================
template<bool ABF>
__global__ __launch_bounds__(256, 1) void sgemm(
    const void* __restrict__ Ap, const short* __restrict__ Btp,
    void* __restrict__ Outp, int K, int M)
{
  constexpr int BM = 32, BN = 128, BK = 64;
  constexpr int ASZ = ABF ? BM*BK*2 : BM*BK*4;
  constexpr int BSZ = BN*BK*2;
  constexpr int TSZ = ASZ + BSZ;
  constexpr int NL  = ABF ? 5 : 6;
  constexpr int NBUF = 3, PRE = 2;
  __shared__ uint8_t lds[NBUF*TSZ];

  const int tid  = threadIdx.x;
  const int lane = tid & 63;
  const int wv   = tid >> 6;
  const int la   = lane & 15;
  const int g4   = lane >> 4;
  const int m0   = blockIdx.x * BM;

  const float* gA0 = nullptr; const float* gA1 = nullptr; const short* gAh = nullptr;
  if constexpr (!ABF){
    const float* Af = (const float*)Ap;
    int r0 = (wv<<3) + (lane>>4);
    int r1 = r0 + 4;
    gA0 = Af + (size_t)(m0+r0)*K + (((lane&15)^(r0&15))<<2);
    gA1 = Af + (size_t)(m0+r1)*K + (((lane&15)^(r1&15))<<2);
  } else {
    const short* Ah = (const short*)Ap;
    int r = (wv<<3) + (lane>>3);
    gAh = Ah + (size_t)(m0+r)*K + (((lane&7)^(r&7))<<3);
  }
  const int nb0 = (wv<<5) + (lane>>3);
  const short* gB0 = Btp + (size_t)(nb0    )*K + (((lane&7)^(nb0&7))<<3);
  const short* gB1 = Btp + (size_t)(nb0+ 8 )*K + (((lane&7)^(nb0&7))<<3);
  const short* gB2 = Btp + (size_t)(nb0+16 )*K + (((lane&7)^(nb0&7))<<3);
  const short* gB3 = Btp + (size_t)(nb0+24 )*K + (((lane&7)^(nb0&7))<<3);

  int aoff[2][2][2];
  int boff[2][2];
#pragma unroll
  for (int mi = 0; mi < 2; ++mi){
    const int r = mi*16 + la;
#pragma unroll
    for (int kf = 0; kf < 2; ++kf){
      if constexpr (!ABF){
        const int v0 = kf*8 + (g4<<1);
        aoff[mi][kf][0] = r*256 + (((v0  )^(r&15))<<4);
        aoff[mi][kf][1] = r*256 + (((v0+1)^(r&15))<<4);
      } else {
        const int u = kf*4 + g4;
        aoff[mi][kf][0] = r*128 + ((u^(r&7))<<4);
        aoff[mi][kf][1] = 0;
      }
    }
  }
#pragma unroll
  for (int ni = 0; ni < 2; ++ni){
    const int n = (wv<<5) + ni*16 + la;
#pragma unroll
    for (int kf = 0; kf < 2; ++kf){
      const int u = kf*4 + g4;
      boff[ni][kf] = n*128 + ((u^(n&7))<<4);
    }
  }

  f32x4 acc[2][2] = {};

  auto STAGE = [&](uint8_t* buf){
    uint8_t* Ab = buf;
    uint8_t* Bb = buf + ASZ;
    if constexpr (!ABF){
      glds16(gA0, Ab + (wv<<11));
      glds16(gA1, Ab + (wv<<11) + 1024);
      gA0 += BK; gA1 += BK;
    } else {
      glds16(gAh, Ab + (wv<<10));
      gAh += BK;
    }
    glds16(gB0, Bb + (wv<<12));
    glds16(gB1, Bb + (wv<<12) + 1024);
    glds16(gB2, Bb + (wv<<12) + 2048);
    glds16(gB3, Bb + (wv<<12) + 3072);
    gB0 += BK; gB1 += BK; gB2 += BK; gB3 += BK;
  };

  auto COMPUTE = [&](const uint8_t* buf){
    const uint8_t* Ab = buf;
    const uint8_t* Bb = buf + ASZ;
#pragma unroll
    for (int kf = 0; kf < 2; ++kf){
      s16x8 a0, a1, b0, b1;
      if constexpr (!ABF){
        a0 = cvt8(*(const f32x4*)(Ab + aoff[0][kf][0]), *(const f32x4*)(Ab + aoff[0][kf][1]));
        a1 = cvt8(*(const f32x4*)(Ab + aoff[1][kf][0]), *(const f32x4*)(Ab + aoff[1][kf][1]));
      } else {
        a0 = *(const s16x8*)(Ab + aoff[0][kf][0]);
        a1 = *(const s16x8*)(Ab + aoff[1][kf][0]);
      }
      b0 = *(const s16x8*)(Bb + boff[0][kf]);
      b1 = *(const s16x8*)(Bb + boff[1][kf]);
      acc[0][0] = __builtin_amdgcn_mfma_f32_16x16x32_bf16(a0, b0, acc[0][0], 0, 0, 0);
      acc[0][1] = __builtin_amdgcn_mfma_f32_16x16x32_bf16(a0, b1, acc[0][1], 0, 0, 0);
      acc[1][0] = __builtin_amdgcn_mfma_f32_16x16x32_bf16(a1, b0, acc[1][0], 0, 0, 0);
      acc[1][1] = __builtin_amdgcn_mfma_f32_16x16x32_bf16(a1, b1, acc[1][1], 0, 0, 0);
    }
  };

  const int ns = K >> 6;
  uint8_t* const lend = lds + NBUF*TSZ;
  uint8_t* bs = lds;
  uint8_t* bc = lds;
  for (int s = 0; s < PRE && s < ns; ++s){
    STAGE(bs);
    bs += TSZ; if (bs == lend) bs = lds;
  }
  for (int t = 0; t < ns; ++t){
    if (t < ns - 1) waitvm<NL>(); else waitvm<0>();
    __builtin_amdgcn_s_barrier();
    asm volatile("" ::: "memory");
    if (t + PRE < ns){
      STAGE(bs);
      bs += TSZ; if (bs == lend) bs = lds;
    }
    COMPUTE(bc);
    bc += TSZ; if (bc == lend) bc = lds;
    asm volatile("" ::: "memory");
  }

  const int mbase = m0 + (g4<<2);
  const int nc0   = (wv<<5) + la;
#pragma unroll
  for (int mi = 0; mi < 2; ++mi){
#pragma unroll
    for (int ni = 0; ni < 2; ++ni){
      s16x4 pk;
#pragma unroll
      for (int r = 0; r < 4; ++r) pk[r] = bf1(acc[mi][ni][r]);
      *(s16x4*)((short*)Outp + (size_t)(nc0 + (ni<<4))*M + (mbase + (mi<<4))) = pk;
    }
  }
}

// ============================================================================
// Reduce kernels: combine 4 K-quarter partials P[4][M][128] (f32).
// ============================================================================

// SPT[n][m] = bf16( f[m] * sum_q P[q][m][n] )  — transpose via LDS.
__global__ __launch_bounds__(256) void red_t(
    const float* __restrict__ Pp, const float* __restrict__ fp,
    short* __restrict__ out, int M)
{
  __shared__ short t[128*65];
  const size_t S = (size_t)M*128;
  const int m0 = blockIdx.x * 64;
  const int tid = threadIdx.x;
#pragma unroll
  for (int it = 0; it < 8; ++it){
    const int idx = it*256 + tid;
    const int m = idx >> 5, nq = idx & 31;
    const float* base = Pp + (size_t)(m0+m)*128;
    f32x4 a = ((const f32x4*)(base      ))[nq];
    f32x4 b = ((const f32x4*)(base +   S))[nq];
    f32x4 c = ((const f32x4*)(base + 2*S))[nq];
    f32x4 d = ((const f32x4*)(base + 3*S))[nq];
    const float fv = fp[m0+m];
#pragma unroll
    for (int j = 0; j < 4; ++j)
      t[(nq*4+j)*65 + m] = bf1(fv * ((a[j] + b[j]) + (c[j] + d[j])));
  }
  __syncthreads();
#pragma unroll
  for (int it = 0; it < 8; ++it){
    const int idx = it*256 + tid;
    const int n = idx >> 4, mc = idx & 15;
    s16x4 v;
#pragma unroll
    for (int j = 0; j < 4; ++j) v[j] = t[n*65 + mc*4 + j];
    *(s16x4*)(out + (size_t)n*M + m0 + mc*4) = v;
  }
}

// H1[i] = bf16( relu(sum_q P[q][i]) )  — row-major, linear.
__global__ __launch_bounds__(256) void red_r(
    const float* __restrict__ Pp, short* __restrict__ out, int M)
{
  const size_t S = (size_t)M*128;
  const size_t i0 = (size_t)(blockIdx.x*256 + threadIdx.x) * 8;
  s16x8 v;
#pragma unroll
  for (int h = 0; h < 2; ++h){
    f32x4 a = *(const f32x4*)(Pp + i0 + 4*h);
    f32x4 b = *(const f32x4*)(Pp + i0 + 4*h + S);
    f32x4 c = *(const f32x4*)(Pp + i0 + 4*h + 2*S);
    f32x4 d = *(const f32x4*)(Pp + i0 + 4*h + 3*S);
#pragma unroll
    for (int j = 0; j < 4; ++j)
      v[4*h+j] = bf1(fmaxf((a[j] + b[j]) + (c[j] + d[j]), 0.0f));
  }
  *(s16x8*)(out + i0) = v;
}

// d_out[i] = sum_q P[q][i]  — f32 row-major, linear.
__global__ __launch_bounds__(256) void red_f(
    const float* __restrict__ Pp, float* __restrict__ out, int M)
{
  const size_t S = (size_t)M*128;
  const size_t i0 = (size_t)(blockIdx.x*256 + threadIdx.x) * 4;
  f32x4 a = *(const f32x4*)(Pp + i0);
  f32x4 b = *(const f32x4*)(Pp + i0 + S);
  f32x4 c = *(const f32x4*)(Pp + i0 + 2*S);
  f32x4 d = *(const f32x4*)(Pp + i0 + 3*S);
  *(f32x4*)(out + i0) = (a + b) + (c + d);
}

// W1T[n][k] = bf16(W1[k][n]), same for W2 — tiny one-shot transpose.
__global__ void wtrans_k(const float* __restrict__ W1, const float* __restrict__ W2,
                         short* __restrict__ T1, short* __restrict__ T2){
  const int idx = blockIdx.x*256 + threadIdx.x;
  const int m = idx >> 14, rem = idx & 16383;
  const int n = rem >> 7, k = rem & 127;
  const float* W = m ? W2 : W1;
  short* T = m ? T2 : T1;
  T[n*128 + k] = bf1(W[k*128 + n]);
}

extern "C" void kernel_launch(void* const* d_in, const int* in_sizes, int n_in,
                              void* d_out, int out_size, void* d_ws, size_t ws_size,
                              hipStream_t stream){
  const float* input = (const float*)d_in[0];
  const float* wav   = (const float*)d_in[1];
  const float* winv  = (const float*)d_in[2];
  const float* W1    = (const float*)d_in[3];
  const float* f1    = (const float*)d_in[4];
  const float* W2    = (const float*)d_in[5];
  const float* f2    = (const float*)d_in[6];

  constexpr int M = 8192;
  uint8_t* ws = (uint8_t*)d_ws;
  short* W1T = (short*)(ws);                        // 32 KB  [n][k]
  short* W2T = (short*)(ws + (32<<10));             // 32 KB  [n][k]
  short* XWT = (short*)(ws + (64<<10));             // 2 MB   [128][M] bf16
  short* SPT = (short*)(ws + (64<<10) + (2<<20));   // 2 MB   [128][M] bf16
  short* H1  = (short*)(ws + (64<<10) + (4<<20));   // 2 MB   [M][128] bf16
  float* P   = (float*)(ws + (64<<10) + (6<<20));   // 16 MB  f32 [4][M][128]
  short* WI16 = (short*)(ws + (64<<10) + (22<<20));         // 128 MB winv bf16
  short* WA16 = WI16 + (size_t)M*M;                          // 128 MB wav bf16
  const size_t needed = (64<<10) + (size_t)(22<<20) + 2*(size_t)M*M*2;
  const bool big = (ws_size >= needed);

  dim3 b(256);
  dim3 gbig(M/128, 4);       // 64 x 4 = 256 blocks, 1/CU
  dim3 gns(M/32);            // small K=128 GEMM
  dim3 grt(M/64);            // red_t
  dim3 grr(M*128/(256*8));   // red_r
  dim3 grf(M*128/(256*4));   // red_f
  dim3 gt(128);

  wtrans_k<<<gt, b, 0, stream>>>(W1, W2, W1T, W2T);
  // layer 1
  sgemm<false><<<gns, b, 0, stream>>>(input, W1T, XWT, 128, M);
  if (big){
    gemm_big<false,true ><<<gbig, b, 0, stream>>>(winv, XWT, P, WI16, M, M);
    red_t<<<grt, b, 0, stream>>>(P, f1, SPT, M);
    gemm_big<false,true ><<<gbig, b, 0, stream>>>(wav, SPT, P, WA16, M, M);
    red_r<<<grr, b, 0, stream>>>(P, H1, M);
    // layer 2 — bf16 A copies
    sgemm<true ><<<gns, b, 0, stream>>>(H1, W2T, XWT, 128, M);
    gemm_big<true ,false><<<gbig, b, 0, stream>>>(WI16, XWT, P, nullptr, M, M);
    red_t<<<grt, b, 0, stream>>>(P, f2, SPT, M);
    gemm_big<true ,false><<<gbig, b, 0, stream>>>(WA16, SPT, P, nullptr, M, M);
    red_f<<<grf, b, 0, stream>>>(P, (float*)d_out, M);
  } else {
    gemm_big<false,false><<<gbig, b, 0, stream>>>(winv, XWT, P, nullptr, M, M);
    red_t<<<grt, b, 0, stream>>>(P, f1, SPT, M);
    gemm_big<false,false><<<gbig, b, 0, stream>>>(wav, SPT, P, nullptr, M, M);
    red_r<<<grr, b, 0, stream>>>(P, H1, M);
    sgemm<true ><<<gns, b, 0, stream>>>(H1, W2T, XWT, 128, M);
    gemm_big<false,false><<<gbig, b, 0, stream>>>(winv, XWT, P, nullptr, M, M);
    red_t<<<grt, b, 0, stream>>>(P, f2, SPT, M);
    gemm_big<false,false><<<gbig, b, 0, stream>>>(wav, SPT, P, nullptr, M, M);
    red_f<<<grf, b, 0, stream>>>(P, (float*)d_out, M);
  }
}

// Round 13
// 315.587 us; speedup vs baseline: 1.1242x; 1.1242x over previous
//
#include <hip/hip_runtime.h>
#include <hip/hip_bf16.h>
#include <stdint.h>

// GWNN: out = L2(relu(L1(x))),  L(x) = W_wav · diag(f) · W_inv · (x·W)
// R13 = R11 (BM=128, split-K x4, NBUF ring, 1 barrier + counted vmcnt/step)
// + FRAGMENT-MAJOR bf16 A copy:
//   G1/G2 (fp32 A) store each wave's own bf16 A-fragments as CONTIGUOUS 1KB
//   full-line writes (fixes R12's 64B half-line RMW disaster).
//   G3/G4 read the copy via gload_lds at its natural pattern (contiguous 1KB
//   per instr, 16KB contiguous per block-step) into linear LDS fragments.
// MODE: 0 = fp32 A + frag-copy out; 1 = bf16 frag-major A; 2 = fp32 plain.

typedef __attribute__((ext_vector_type(4))) float f32x4;
typedef __attribute__((ext_vector_type(8))) short s16x8;
typedef __attribute__((ext_vector_type(4))) short s16x4;

#define DEVI static __device__ __forceinline__

DEVI short bf1(float x){ __bf16 h = (__bf16)x; return __builtin_bit_cast(short, h); }

DEVI s16x8 cvt8(f32x4 lo, f32x4 hi){
  s16x8 r;
#pragma unroll
  for (int i = 0; i < 4; ++i){ r[i] = bf1(lo[i]); r[4+i] = bf1(hi[i]); }
  return r;
}

DEVI void glds16(const void* g, void* l){
  __builtin_amdgcn_global_load_lds((const __attribute__((address_space(1))) void*)g,
                                   (__attribute__((address_space(3))) void*)l, 16, 0, 0);
}

template<int N> DEVI void waitvm(){
  if constexpr (N == 0)       asm volatile("s_waitcnt vmcnt(0)"  ::: "memory");
  else if constexpr (N == 5)  asm volatile("s_waitcnt vmcnt(5)"  ::: "memory");
  else if constexpr (N == 6)  asm volatile("s_waitcnt vmcnt(6)"  ::: "memory");
  else if constexpr (N == 8)  asm volatile("s_waitcnt vmcnt(8)"  ::: "memory");
  else if constexpr (N == 12) asm volatile("s_waitcnt vmcnt(12)" ::: "memory");
  else if constexpr (N == 16) asm volatile("s_waitcnt vmcnt(16)" ::: "memory");
  else if constexpr (N == 20) asm volatile("s_waitcnt vmcnt(20)" ::: "memory");
}

// ============================================================================
// Big GEMM, BM=128, split-K x4: P[kq][M][128] = A @ Bt^T  (f32 partials).
// MODE 0: A fp32 row-major, cvt at LDS read, store bf16 frags to Cp
//         (frag-major: Cp[(kq*64+bx)*512KB + t*16KB + wv*4KB + j*1KB + lane*16B],
//          j = mi*2+kf). Every store instr = contiguous 1KB full lines.
// MODE 1: A = the frag-major copy; gload_lds contiguous 1KB per instr,
//         linear LDS fragments (no XOR), NBUF=4 depth 3.
// MODE 2: A fp32 plain (R11 behavior; ws fallback).
// ============================================================================
template<int MODE>
__global__ __launch_bounds__(256, 1) void gemm_big(
    const void* __restrict__ Ap, const short* __restrict__ Btp,
    float* __restrict__ Pp, short* __restrict__ Cp, int K, int M)
{
  constexpr bool ABF = (MODE == 1);
  constexpr bool WCP = (MODE == 0);
  constexpr int BM = 128, BK = 64;
  constexpr int ASZ = ABF ? 16384 : 32768;   // bf16 16 KB / fp32 32 KB
  constexpr int BSZ = 16384;                 // 16 KB
  constexpr int TSZ = ASZ + BSZ;             // 32 / 48 KB
  constexpr int NBUF = ABF ? 4 : 3;          // 128 / 144 KB
  constexpr int PRE  = ABF ? 3 : 2;
  __shared__ uint8_t lds[NBUF*TSZ];

  const int tid  = threadIdx.x;
  const int lane = tid & 63;
  const int wv   = tid >> 6;
  const int la   = lane & 15;
  const int g4   = lane >> 4;
  const int bx   = blockIdx.x;
  const int kq   = blockIdx.y;
  const int m0   = bx * BM;
  const int K4   = K >> 2;
  const int kb   = kq * K4;

  // ---- A staging addresses
  const float* gAf = nullptr; const short* gAq = nullptr;
  int aoffg[8];
  if constexpr (!ABF){
    gAf = (const float*)Ap + (size_t)m0*K + kb;
#pragma unroll
    for (int j = 0; j < 8; ++j){
      const int rl = (wv<<5) + (j<<2) + (lane>>4);       // 4 rows / instr
      aoffg[j] = rl*K + (((lane&15) ^ (rl&15))<<2);
    }
  } else {
    // fragment-major copy: per (kq,bx) region = 32 steps x 8192 shorts
    gAq = (const short*)Ap + (size_t)(kq*64 + bx)*262144 + (wv<<11) + (lane<<3);
  }

  // ---- B staging (proven): wave w stages B rows 32w..32w+31, pre-swizzled
  const int nb0 = (wv<<5) + (lane>>3);
  const short* gB0 = Btp + (size_t)(nb0    )*K + kb + (((lane&7)^(nb0&7))<<3);
  const short* gB1 = Btp + (size_t)(nb0+ 8 )*K + kb + (((lane&7)^(nb0&7))<<3);
  const short* gB2 = Btp + (size_t)(nb0+16 )*K + kb + (((lane&7)^(nb0&7))<<3);
  const short* gB3 = Btp + (size_t)(nb0+24 )*K + kb + (((lane&7)^(nb0&7))<<3);

  // ---- fragment LDS byte offsets
  int aoff[2][2][2];   // [mi][kf][part]
#pragma unroll
  for (int mi = 0; mi < 2; ++mi){
#pragma unroll
    for (int kf = 0; kf < 2; ++kf){
      if constexpr (!ABF){
        const int r = (wv<<5) + mi*16 + la;              // XOR-swizzled fp32
        const int v0 = kf*8 + (g4<<1);
        aoff[mi][kf][0] = r*256 + (((v0  )^(r&15))<<4);
        aoff[mi][kf][1] = r*256 + (((v0+1)^(r&15))<<4);
      } else {
        // linear fragment: wv*4KB + j*1KB + lane*16
        aoff[mi][kf][0] = (wv<<12) + (((mi<<1)+kf)<<10) + (lane<<4);
        aoff[mi][kf][1] = 0;
      }
    }
  }
  int boff[8][2];      // [ni][kf]
#pragma unroll
  for (int ni = 0; ni < 8; ++ni){
    const int n = ni*16 + la;
#pragma unroll
    for (int kf = 0; kf < 2; ++kf){
      const int u = kf*4 + g4;
      boff[ni][kf] = n*128 + ((u^(n&7))<<4);
    }
  }

  // ---- frag-copy store base (MODE 0): contiguous 1KB per store instr
  short* cw = nullptr;
  if constexpr (WCP)
    cw = Cp + (size_t)(kq*64 + bx)*262144 + (wv<<11) + (lane<<3);

  f32x4 acc[2][8] = {};

  int kk = 0;     // staging advance (fp32 elements / shorts)
  int kc = 0;     // copy-store advance (shorts)
  uint8_t* const lend = lds + NBUF*TSZ;
  uint8_t* bs = lds;
  uint8_t* bc = lds;

  auto STAGE = [&](){
    uint8_t* Ab = bs;
    uint8_t* Bb = bs + ASZ;
    if constexpr (!ABF){
#pragma unroll
      for (int j = 0; j < 8; ++j)
        glds16(gAf + aoffg[j] + kk, Ab + (wv<<13) + (j<<10));
      kk += BK;
    } else {
#pragma unroll
      for (int j = 0; j < 4; ++j)
        glds16(gAq + kk + (j<<9), Ab + (wv<<12) + (j<<10));
      kk += 8192;                       // one step = 8192 shorts (16 KB)
    }
    glds16(gB0, Bb + (wv<<12));
    glds16(gB1, Bb + (wv<<12) + 1024);
    glds16(gB2, Bb + (wv<<12) + 2048);
    glds16(gB3, Bb + (wv<<12) + 3072);
    gB0 += BK; gB1 += BK; gB2 += BK; gB3 += BK;
    bs += TSZ; if (bs == lend) bs = lds;
  };

  auto COMPUTE = [&](){
    const uint8_t* Ab = bc;
    const uint8_t* Bb = bc + ASZ;
#pragma unroll
    for (int kf = 0; kf < 2; ++kf){
      s16x8 a0, a1;
      if constexpr (!ABF){
        a0 = cvt8(*(const f32x4*)(Ab + aoff[0][kf][0]),
                  *(const f32x4*)(Ab + aoff[0][kf][1]));
        a1 = cvt8(*(const f32x4*)(Ab + aoff[1][kf][0]),
                  *(const f32x4*)(Ab + aoff[1][kf][1]));
        if constexpr (WCP){
          *(s16x8*)(cw + kc + (kf<<9))       = a0;   // j = kf      (1KB line)
          *(s16x8*)(cw + kc + ((2+kf)<<9))   = a1;   // j = 2+kf    (1KB line)
        }
      } else {
        a0 = *(const s16x8*)(Ab + aoff[0][kf][0]);
        a1 = *(const s16x8*)(Ab + aoff[1][kf][0]);
      }
#pragma unroll
      for (int ni = 0; ni < 8; ++ni){
        s16x8 b = *(const s16x8*)(Bb + boff[ni][kf]);
        acc[0][ni] = __builtin_amdgcn_mfma_f32_16x16x32_bf16(a0, b, acc[0][ni], 0, 0, 0);
        acc[1][ni] = __builtin_amdgcn_mfma_f32_16x16x32_bf16(a1, b, acc[1][ni], 0, 0, 0);
      }
    }
    if constexpr (WCP) kc += 8192;
    bc += TSZ; if (bc == lend) bc = lds;
  };

  const int ns = K4 >> 6;                    // 32 steps
  for (int s = 0; s < PRE && s < ns; ++s) STAGE();

  for (int t = 0; t < ns; ++t){
    if constexpr (ABF){                      // 8 ops/stage, depth 3
      if (t <= ns - 3)      waitvm<16>();
      else if (t == ns - 2) waitvm<8>();
      else                  waitvm<0>();
    } else if constexpr (WCP){               // 12 ops/stage + 4 stores/step
      if (t == 0)           waitvm<12>();
      else if (t == 1)      waitvm<16>();
      else if (t <= ns - 2) waitvm<20>();
      else                  waitvm<0>();
    } else {
      if (t < ns - 1) waitvm<12>(); else waitvm<0>();
    }
    __builtin_amdgcn_s_barrier();
    asm volatile("" ::: "memory");
    if (t + PRE < ns) STAGE();
    COMPUTE();
    asm volatile("" ::: "memory");
  }

  // ---- partial epilogue: f32 P[kq][M][128]
  float* P = Pp + (size_t)kq * M * 128;
  const int rbase = m0 + (wv<<5) + (g4<<2);
#pragma unroll
  for (int mi = 0; mi < 2; ++mi)
#pragma unroll
    for (int ni = 0; ni < 8; ++ni)
#pragma unroll
      for (int r = 0; r < 4; ++r)
        P[(size_t)(rbase + mi*16 + r)*128 + ni*16 + la] = acc[mi][ni][r];
}

// ============================================================================
// Small K=128 GEMM (proven): out = bf16 transposed [128][M].
// ============================================================================
template<bool ABF>
__global__ __launch_bounds__(256, 1) void sgemm(
    const void* __restrict__ Ap, const short* __restrict__ Btp,
    void* __restrict__ Outp, int K, int M)
{
  constexpr int BM = 32, BN = 128, BK = 64;
  constexpr int ASZ = ABF ? BM*BK*2 : BM*BK*4;
  constexpr int BSZ = BN*BK*2;
  constexpr int TSZ = ASZ + BSZ;
  constexpr int NL  = ABF ? 5 : 6;
  constexpr int NBUF = 3, PRE = 2;
  __shared__ uint8_t lds[NBUF*TSZ];

  const int tid  = threadIdx.x;
  const int lane = tid & 63;
  const int wv   = tid >> 6;
  const int la   = lane & 15;
  const int g4   = lane >> 4;
  const int m0   = blockIdx.x * BM;

  const float* gA0 = nullptr; const float* gA1 = nullptr; const short* gAh = nullptr;
  if constexpr (!ABF){
    const float* Af = (const float*)Ap;
    int r0 = (wv<<3) + (lane>>4);
    int r1 = r0 + 4;
    gA0 = Af + (size_t)(m0+r0)*K + (((lane&15)^(r0&15))<<2);
    gA1 = Af + (size_t)(m0+r1)*K + (((lane&15)^(r1&15))<<2);
  } else {
    const short* Ah = (const short*)Ap;
    int r = (wv<<3) + (lane>>3);
    gAh = Ah + (size_t)(m0+r)*K + (((lane&7)^(r&7))<<3);
  }
  const int nb0 = (wv<<5) + (lane>>3);
  const short* gB0 = Btp + (size_t)(nb0    )*K + (((lane&7)^(nb0&7))<<3);
  const short* gB1 = Btp + (size_t)(nb0+ 8 )*K + (((lane&7)^(nb0&7))<<3);
  const short* gB2 = Btp + (size_t)(nb0+16 )*K + (((lane&7)^(nb0&7))<<3);
  const short* gB3 = Btp + (size_t)(nb0+24 )*K + (((lane&7)^(nb0&7))<<3);

  int aoff[2][2][2];
  int boff[2][2];
#pragma unroll
  for (int mi = 0; mi < 2; ++mi){
    const int r = mi*16 + la;
#pragma unroll
    for (int kf = 0; kf < 2; ++kf){
      if constexpr (!ABF){
        const int v0 = kf*8 + (g4<<1);
        aoff[mi][kf][0] = r*256 + (((v0  )^(r&15))<<4);
        aoff[mi][kf][1] = r*256 + (((v0+1)^(r&15))<<4);
      } else {
        const int u = kf*4 + g4;
        aoff[mi][kf][0] = r*128 + ((u^(r&7))<<4);
        aoff[mi][kf][1] = 0;
      }
    }
  }
#pragma unroll
  for (int ni = 0; ni < 2; ++ni){
    const int n = (wv<<5) + ni*16 + la;
#pragma unroll
    for (int kf = 0; kf < 2; ++kf){
      const int u = kf*4 + g4;
      boff[ni][kf] = n*128 + ((u^(n&7))<<4);
    }
  }

  f32x4 acc[2][2] = {};

  auto STAGE = [&](uint8_t* buf){
    uint8_t* Ab = buf;
    uint8_t* Bb = buf + ASZ;
    if constexpr (!ABF){
      glds16(gA0, Ab + (wv<<11));
      glds16(gA1, Ab + (wv<<11) + 1024);
      gA0 += BK; gA1 += BK;
    } else {
      glds16(gAh, Ab + (wv<<10));
      gAh += BK;
    }
    glds16(gB0, Bb + (wv<<12));
    glds16(gB1, Bb + (wv<<12) + 1024);
    glds16(gB2, Bb + (wv<<12) + 2048);
    glds16(gB3, Bb + (wv<<12) + 3072);
    gB0 += BK; gB1 += BK; gB2 += BK; gB3 += BK;
  };

  auto COMPUTE = [&](const uint8_t* buf){
    const uint8_t* Ab = buf;
    const uint8_t* Bb = buf + ASZ;
#pragma unroll
    for (int kf = 0; kf < 2; ++kf){
      s16x8 a0, a1, b0, b1;
      if constexpr (!ABF){
        a0 = cvt8(*(const f32x4*)(Ab + aoff[0][kf][0]), *(const f32x4*)(Ab + aoff[0][kf][1]));
        a1 = cvt8(*(const f32x4*)(Ab + aoff[1][kf][0]), *(const f32x4*)(Ab + aoff[1][kf][1]));
      } else {
        a0 = *(const s16x8*)(Ab + aoff[0][kf][0]);
        a1 = *(const s16x8*)(Ab + aoff[1][kf][0]);
      }
      b0 = *(const s16x8*)(Bb + boff[0][kf]);
      b1 = *(const s16x8*)(Bb + boff[1][kf]);
      acc[0][0] = __builtin_amdgcn_mfma_f32_16x16x32_bf16(a0, b0, acc[0][0], 0, 0, 0);
      acc[0][1] = __builtin_amdgcn_mfma_f32_16x16x32_bf16(a0, b1, acc[0][1], 0, 0, 0);
      acc[1][0] = __builtin_amdgcn_mfma_f32_16x16x32_bf16(a1, b0, acc[1][0], 0, 0, 0);
      acc[1][1] = __builtin_amdgcn_mfma_f32_16x16x32_bf16(a1, b1, acc[1][1], 0, 0, 0);
    }
  };

  const int ns = K >> 6;
  uint8_t* const lend = lds + NBUF*TSZ;
  uint8_t* bs = lds;
  uint8_t* bc = lds;
  for (int s = 0; s < PRE && s < ns; ++s){
    STAGE(bs);
    bs += TSZ; if (bs == lend) bs = lds;
  }
  for (int t = 0; t < ns; ++t){
    if (t < ns - 1) waitvm<NL>(); else waitvm<0>();
    __builtin_amdgcn_s_barrier();
    asm volatile("" ::: "memory");
    if (t + PRE < ns){
      STAGE(bs);
      bs += TSZ; if (bs == lend) bs = lds;
    }
    COMPUTE(bc);
    bc += TSZ; if (bc == lend) bc = lds;
    asm volatile("" ::: "memory");
  }

  const int mbase = m0 + (g4<<2);
  const int nc0   = (wv<<5) + la;
#pragma unroll
  for (int mi = 0; mi < 2; ++mi){
#pragma unroll
    for (int ni = 0; ni < 2; ++ni){
      s16x4 pk;
#pragma unroll
      for (int r = 0; r < 4; ++r) pk[r] = bf1(acc[mi][ni][r]);
      *(s16x4*)((short*)Outp + (size_t)(nc0 + (ni<<4))*M + (mbase + (mi<<4))) = pk;
    }
  }
}

// ============================================================================
// Reduce kernels: combine 4 K-quarter partials P[4][M][128] (f32).
// ============================================================================

__global__ __launch_bounds__(256) void red_t(
    const float* __restrict__ Pp, const float* __restrict__ fp,
    short* __restrict__ out, int M)
{
  __shared__ short t[128*65];
  const size_t S = (size_t)M*128;
  const int m0 = blockIdx.x * 64;
  const int tid = threadIdx.x;
#pragma unroll
  for (int it = 0; it < 8; ++it){
    const int idx = it*256 + tid;
    const int m = idx >> 5, nq = idx & 31;
    const float* base = Pp + (size_t)(m0+m)*128;
    f32x4 a = ((const f32x4*)(base      ))[nq];
    f32x4 b = ((const f32x4*)(base +   S))[nq];
    f32x4 c = ((const f32x4*)(base + 2*S))[nq];
    f32x4 d = ((const f32x4*)(base + 3*S))[nq];
    const float fv = fp[m0+m];
#pragma unroll
    for (int j = 0; j < 4; ++j)
      t[(nq*4+j)*65 + m] = bf1(fv * ((a[j] + b[j]) + (c[j] + d[j])));
  }
  __syncthreads();
#pragma unroll
  for (int it = 0; it < 8; ++it){
    const int idx = it*256 + tid;
    const int n = idx >> 4, mc = idx & 15;
    s16x4 v;
#pragma unroll
    for (int j = 0; j < 4; ++j) v[j] = t[n*65 + mc*4 + j];
    *(s16x4*)(out + (size_t)n*M + m0 + mc*4) = v;
  }
}

__global__ __launch_bounds__(256) void red_r(
    const float* __restrict__ Pp, short* __restrict__ out, int M)
{
  const size_t S = (size_t)M*128;
  const size_t i0 = (size_t)(blockIdx.x*256 + threadIdx.x) * 8;
  s16x8 v;
#pragma unroll
  for (int h = 0; h < 2; ++h){
    f32x4 a = *(const f32x4*)(Pp + i0 + 4*h);
    f32x4 b = *(const f32x4*)(Pp + i0 + 4*h + S);
    f32x4 c = *(const f32x4*)(Pp + i0 + 4*h + 2*S);
    f32x4 d = *(const f32x4*)(Pp + i0 + 4*h + 3*S);
#pragma unroll
    for (int j = 0; j < 4; ++j)
      v[4*h+j] = bf1(fmaxf((a[j] + b[j]) + (c[j] + d[j]), 0.0f));
  }
  *(s16x8*)(out + i0) = v;
}

__global__ __launch_bounds__(256) void red_f(
    const float* __restrict__ Pp, float* __restrict__ out, int M)
{
  const size_t S = (size_t)M*128;
  const size_t i0 = (size_t)(blockIdx.x*256 + threadIdx.x) * 4;
  f32x4 a = *(const f32x4*)(Pp + i0);
  f32x4 b = *(const f32x4*)(Pp + i0 + S);
  f32x4 c = *(const f32x4*)(Pp + i0 + 2*S);
  f32x4 d = *(const f32x4*)(Pp + i0 + 3*S);
  *(f32x4*)(out + i0) = (a + b) + (c + d);
}

// W1T[n][k] = bf16(W1[k][n]), same for W2 — tiny one-shot transpose.
__global__ void wtrans_k(const float* __restrict__ W1, const float* __restrict__ W2,
                         short* __restrict__ T1, short* __restrict__ T2){
  const int idx = blockIdx.x*256 + threadIdx.x;
  const int m = idx >> 14, rem = idx & 16383;
  const int n = rem >> 7, k = rem & 127;
  const float* W = m ? W2 : W1;
  short* T = m ? T2 : T1;
  T[n*128 + k] = bf1(W[k*128 + n]);
}

extern "C" void kernel_launch(void* const* d_in, const int* in_sizes, int n_in,
                              void* d_out, int out_size, void* d_ws, size_t ws_size,
                              hipStream_t stream){
  const float* input = (const float*)d_in[0];
  const float* wav   = (const float*)d_in[1];
  const float* winv  = (const float*)d_in[2];
  const float* W1    = (const float*)d_in[3];
  const float* f1    = (const float*)d_in[4];
  const float* W2    = (const float*)d_in[5];
  const float* f2    = (const float*)d_in[6];

  constexpr int M = 8192;
  uint8_t* ws = (uint8_t*)d_ws;
  short* W1T = (short*)(ws);                        // 32 KB  [n][k]
  short* W2T = (short*)(ws + (32<<10));             // 32 KB  [n][k]
  short* XWT = (short*)(ws + (64<<10));             // 2 MB   [128][M] bf16
  short* SPT = (short*)(ws + (64<<10) + (2<<20));   // 2 MB   [128][M] bf16
  short* H1  = (short*)(ws + (64<<10) + (4<<20));   // 2 MB   [M][128] bf16
  float* P   = (float*)(ws + (64<<10) + (6<<20));   // 16 MB  f32 [4][M][128]
  short* WI16 = (short*)(ws + (64<<10) + (22<<20)); // 128 MB winv bf16 frag-major
  short* WA16 = WI16 + (size_t)M*M;                 // 128 MB wav  bf16 frag-major
  const size_t needed = (64<<10) + (size_t)(22<<20) + 2*(size_t)M*M*2;
  const bool big = (ws_size >= needed);

  dim3 b(256);
  dim3 gbig(M/128, 4);       // 64 x 4 = 256 blocks, 1/CU
  dim3 gns(M/32);            // small K=128 GEMM
  dim3 grt(M/64);            // red_t
  dim3 grr(M*128/(256*8));   // red_r
  dim3 grf(M*128/(256*4));   // red_f
  dim3 gt(128);

  wtrans_k<<<gt, b, 0, stream>>>(W1, W2, W1T, W2T);
  sgemm<false><<<gns, b, 0, stream>>>(input, W1T, XWT, 128, M);
  if (big){
    // layer 1: fp32 A + coalesced fragment-copy out
    gemm_big<0><<<gbig, b, 0, stream>>>(winv, XWT, P, WI16, M, M);
    red_t<<<grt, b, 0, stream>>>(P, f1, SPT, M);
    gemm_big<0><<<gbig, b, 0, stream>>>(wav, SPT, P, WA16, M, M);
    red_r<<<grr, b, 0, stream>>>(P, H1, M);
    // layer 2: bf16 fragment-major A
    sgemm<true ><<<gns, b, 0, stream>>>(H1, W2T, XWT, 128, M);
    gemm_big<1><<<gbig, b, 0, stream>>>(WI16, XWT, P, nullptr, M, M);
    red_t<<<grt, b, 0, stream>>>(P, f2, SPT, M);
    gemm_big<1><<<gbig, b, 0, stream>>>(WA16, SPT, P, nullptr, M, M);
    red_f<<<grf, b, 0, stream>>>(P, (float*)d_out, M);
  } else {
    gemm_big<2><<<gbig, b, 0, stream>>>(winv, XWT, P, nullptr, M, M);
    red_t<<<grt, b, 0, stream>>>(P, f1, SPT, M);
    gemm_big<2><<<gbig, b, 0, stream>>>(wav, SPT, P, nullptr, M, M);
    red_r<<<grr, b, 0, stream>>>(P, H1, M);
    sgemm<true ><<<gns, b, 0, stream>>>(H1, W2T, XWT, 128, M);
    gemm_big<2><<<gbig, b, 0, stream>>>(winv, XWT, P, nullptr, M, M);
    red_t<<<grt, b, 0, stream>>>(P, f2, SPT, M);
    gemm_big<2><<<gbig, b, 0, stream>>>(wav, SPT, P, nullptr, M, M);
    red_f<<<grf, b, 0, stream>>>(P, (float*)d_out, M);
  }
}

// Round 14
// 290.161 us; speedup vs baseline: 1.2227x; 1.0876x over previous
//
#include <hip/hip_runtime.h>
#include <hip/hip_bf16.h>
#include <stdint.h>

// GWNN: out = L2(relu(L1(x))),  L(x) = W_wav · diag(f) · W_inv · (x·W)
// R14 = R11 (best: BM=128, split-K x4, NBUF=3 ring, 1 barrier + counted
// vmcnt(12)/step, f32 partials + fused reduce kernels) + T1 XCD swizzle:
// logical m-tile = (bx%8)*8 + bx/8 so each XCD owns a CONTIGUOUS 1024-row
// (32MB) slab of A instead of 8 scattered slabs -> L2/DRAM-channel locality.
// (R12/R13 bf16-copy family reverted: measured net-neutral to negative.)

typedef __attribute__((ext_vector_type(4))) float f32x4;
typedef __attribute__((ext_vector_type(8))) short s16x8;
typedef __attribute__((ext_vector_type(4))) short s16x4;

#define DEVI static __device__ __forceinline__

DEVI short bf1(float x){ __bf16 h = (__bf16)x; return __builtin_bit_cast(short, h); }

DEVI s16x8 cvt8(f32x4 lo, f32x4 hi){
  s16x8 r;
#pragma unroll
  for (int i = 0; i < 4; ++i){ r[i] = bf1(lo[i]); r[4+i] = bf1(hi[i]); }
  return r;
}

DEVI void glds16(const void* g, void* l){
  __builtin_amdgcn_global_load_lds((const __attribute__((address_space(1))) void*)g,
                                   (__attribute__((address_space(3))) void*)l, 16, 0, 0);
}

template<int N> DEVI void waitvm(){
  if constexpr (N == 0)       asm volatile("s_waitcnt vmcnt(0)"  ::: "memory");
  else if constexpr (N == 5)  asm volatile("s_waitcnt vmcnt(5)"  ::: "memory");
  else if constexpr (N == 6)  asm volatile("s_waitcnt vmcnt(6)"  ::: "memory");
  else if constexpr (N == 12) asm volatile("s_waitcnt vmcnt(12)" ::: "memory");
}

// ============================================================================
// Big GEMM, BM=128, split-K x4: P[kq][M][128] = A[M, kq-quarter](f32) @ Bt^T
// Bt bf16 row-major [128][K]. Wave w owns rows 32w..32w+31: acc[2][8],
// 32 MFMA/wave/step, no A-read duplication. 12 gload_lds/wave/stage.
// XCD swizzle: logical m-tile bxl = (bx%8)*8 + bx/8  (bijective, 64 tiles).
// ============================================================================
__global__ __launch_bounds__(256, 1) void gemm_big(
    const float* __restrict__ Ap, const short* __restrict__ Btp,
    float* __restrict__ Pp, int K, int M)
{
  constexpr int BM = 128, BK = 64;
  constexpr int ASZ = BM*BK*4;     // 32 KB fp32 A tile
  constexpr int BSZ = 128*BK*2;    // 16 KB B tile
  constexpr int TSZ = ASZ + BSZ;   // 48 KB
  constexpr int NBUF = 3, PRE = 2; // 144 KB LDS
  __shared__ uint8_t lds[NBUF*TSZ];

  const int tid  = threadIdx.x;
  const int lane = tid & 63;
  const int wv   = tid >> 6;
  const int la   = lane & 15;
  const int g4   = lane >> 4;
  const int bxl  = ((blockIdx.x & 7) << 3) + (blockIdx.x >> 3);  // T1 swizzle
  const int m0   = bxl * BM;
  const int kq   = blockIdx.y;
  const int K4   = K >> 2;
  const int kb   = kq * K4;

  // ---- A staging: wave w, instr j (0..7) stages local rows 32w+4j..+3.
  const float* gAbase = Ap + (size_t)m0*K + kb;
  int aoffg[8];
#pragma unroll
  for (int j = 0; j < 8; ++j){
    const int rl = (wv<<5) + (j<<2) + (lane>>4);        // local row 0..127
    aoffg[j] = rl*K + (((lane&15) ^ (rl&15))<<2);       // float offset
  }

  // ---- B staging (proven): wave w stages rows 32w..32w+31, pre-swizzled
  const int nb0 = (wv<<5) + (lane>>3);
  const short* gB0 = Btp + (size_t)(nb0    )*K + kb + (((lane&7)^(nb0&7))<<3);
  const short* gB1 = Btp + (size_t)(nb0+ 8 )*K + kb + (((lane&7)^(nb0&7))<<3);
  const short* gB2 = Btp + (size_t)(nb0+16 )*K + kb + (((lane&7)^(nb0&7))<<3);
  const short* gB3 = Btp + (size_t)(nb0+24 )*K + kb + (((lane&7)^(nb0&7))<<3);

  // ---- fragment LDS byte offsets (XOR-swizzled reads)
  int aoff[2][2][2];   // [mi][kf][part]; fp32 row = 16 x 16B units
#pragma unroll
  for (int mi = 0; mi < 2; ++mi){
    const int r = (wv<<5) + mi*16 + la;                 // wave-private rows
#pragma unroll
    for (int kf = 0; kf < 2; ++kf){
      const int v0 = kf*8 + (g4<<1);
      aoff[mi][kf][0] = r*256 + (((v0  )^(r&15))<<4);
      aoff[mi][kf][1] = r*256 + (((v0+1)^(r&15))<<4);
    }
  }
  int boff[8][2];      // [ni][kf]; all 128 cols per wave
#pragma unroll
  for (int ni = 0; ni < 8; ++ni){
    const int n = ni*16 + la;
#pragma unroll
    for (int kf = 0; kf < 2; ++kf){
      const int u = kf*4 + g4;
      boff[ni][kf] = n*128 + ((u^(n&7))<<4);
    }
  }

  f32x4 acc[2][8] = {};

  int kk = 0;                                // A k-advance (floats)
  uint8_t* const lend = lds + NBUF*TSZ;
  uint8_t* bs = lds;
  uint8_t* bc = lds;

  auto STAGE = [&](){
    uint8_t* Ab = bs;
    uint8_t* Bb = bs + ASZ;
#pragma unroll
    for (int j = 0; j < 8; ++j)
      glds16(gAbase + aoffg[j] + kk, Ab + (wv<<13) + (j<<10));
    kk += BK;
    glds16(gB0, Bb + (wv<<12));
    glds16(gB1, Bb + (wv<<12) + 1024);
    glds16(gB2, Bb + (wv<<12) + 2048);
    glds16(gB3, Bb + (wv<<12) + 3072);
    gB0 += BK; gB1 += BK; gB2 += BK; gB3 += BK;
    bs += TSZ; if (bs == lend) bs = lds;
  };

  auto COMPUTE = [&](){
    const uint8_t* Ab = bc;
    const uint8_t* Bb = bc + ASZ;
#pragma unroll
    for (int kf = 0; kf < 2; ++kf){
      s16x8 a0 = cvt8(*(const f32x4*)(Ab + aoff[0][kf][0]),
                      *(const f32x4*)(Ab + aoff[0][kf][1]));
      s16x8 a1 = cvt8(*(const f32x4*)(Ab + aoff[1][kf][0]),
                      *(const f32x4*)(Ab + aoff[1][kf][1]));
#pragma unroll
      for (int ni = 0; ni < 8; ++ni){
        s16x8 b = *(const s16x8*)(Bb + boff[ni][kf]);
        acc[0][ni] = __builtin_amdgcn_mfma_f32_16x16x32_bf16(a0, b, acc[0][ni], 0, 0, 0);
        acc[1][ni] = __builtin_amdgcn_mfma_f32_16x16x32_bf16(a1, b, acc[1][ni], 0, 0, 0);
      }
    }
    bc += TSZ; if (bc == lend) bc = lds;
  };

  const int ns = K4 >> 6;                    // 32 steps
  for (int s = 0; s < PRE && s < ns; ++s) STAGE();

  for (int t = 0; t < ns; ++t){
    if (t < ns - 1) waitvm<12>();            // stage t landed; t+1 in flight
    else            waitvm<0>();
    __builtin_amdgcn_s_barrier();
    asm volatile("" ::: "memory");
    if (t + PRE < ns) STAGE();
    COMPUTE();
    asm volatile("" ::: "memory");
  }

  // ---- partial epilogue: f32 P[kq][M][128]
  float* P = Pp + (size_t)kq * M * 128;
  const int rbase = m0 + (wv<<5) + (g4<<2);
#pragma unroll
  for (int mi = 0; mi < 2; ++mi)
#pragma unroll
    for (int ni = 0; ni < 8; ++ni)
#pragma unroll
      for (int r = 0; r < 4; ++r)
        P[(size_t)(rbase + mi*16 + r)*128 + ni*16 + la] = acc[mi][ni][r];
}

// ============================================================================
// Small K=128 GEMM (proven): out = bf16 transposed [128][M].
// ============================================================================
template<bool ABF>
__global__ __launch_bounds__(256, 1) void sgemm(
    const void* __restrict__ Ap, const short* __restrict__ Btp,
    void* __restrict__ Outp, int K, int M)
{
  constexpr int BM = 32, BN = 128, BK = 64;
  constexpr int ASZ = ABF ? BM*BK*2 : BM*BK*4;
  constexpr int BSZ = BN*BK*2;
  constexpr int TSZ = ASZ + BSZ;
  constexpr int NL  = ABF ? 5 : 6;
  constexpr int NBUF = 3, PRE = 2;
  __shared__ uint8_t lds[NBUF*TSZ];

  const int tid  = threadIdx.x;
  const int lane = tid & 63;
  const int wv   = tid >> 6;
  const int la   = lane & 15;
  const int g4   = lane >> 4;
  const int m0   = blockIdx.x * BM;

  const float* gA0 = nullptr; const float* gA1 = nullptr; const short* gAh = nullptr;
  if constexpr (!ABF){
    const float* Af = (const float*)Ap;
    int r0 = (wv<<3) + (lane>>4);
    int r1 = r0 + 4;
    gA0 = Af + (size_t)(m0+r0)*K + (((lane&15)^(r0&15))<<2);
    gA1 = Af + (size_t)(m0+r1)*K + (((lane&15)^(r1&15))<<2);
  } else {
    const short* Ah = (const short*)Ap;
    int r = (wv<<3) + (lane>>3);
    gAh = Ah + (size_t)(m0+r)*K + (((lane&7)^(r&7))<<3);
  }
  const int nb0 = (wv<<5) + (lane>>3);
  const short* gB0 = Btp + (size_t)(nb0    )*K + (((lane&7)^(nb0&7))<<3);
  const short* gB1 = Btp + (size_t)(nb0+ 8 )*K + (((lane&7)^(nb0&7))<<3);
  const short* gB2 = Btp + (size_t)(nb0+16 )*K + (((lane&7)^(nb0&7))<<3);
  const short* gB3 = Btp + (size_t)(nb0+24 )*K + (((lane&7)^(nb0&7))<<3);

  int aoff[2][2][2];
  int boff[2][2];
#pragma unroll
  for (int mi = 0; mi < 2; ++mi){
    const int r = mi*16 + la;
#pragma unroll
    for (int kf = 0; kf < 2; ++kf){
      if constexpr (!ABF){
        const int v0 = kf*8 + (g4<<1);
        aoff[mi][kf][0] = r*256 + (((v0  )^(r&15))<<4);
        aoff[mi][kf][1] = r*256 + (((v0+1)^(r&15))<<4);
      } else {
        const int u = kf*4 + g4;
        aoff[mi][kf][0] = r*128 + ((u^(r&7))<<4);
        aoff[mi][kf][1] = 0;
      }
    }
  }
#pragma unroll
  for (int ni = 0; ni < 2; ++ni){
    const int n = (wv<<5) + ni*16 + la;
#pragma unroll
    for (int kf = 0; kf < 2; ++kf){
      const int u = kf*4 + g4;
      boff[ni][kf] = n*128 + ((u^(n&7))<<4);
    }
  }

  f32x4 acc[2][2] = {};

  auto STAGE = [&](uint8_t* buf){
    uint8_t* Ab = buf;
    uint8_t* Bb = buf + ASZ;
    if constexpr (!ABF){
      glds16(gA0, Ab + (wv<<11));
      glds16(gA1, Ab + (wv<<11) + 1024);
      gA0 += BK; gA1 += BK;
    } else {
      glds16(gAh, Ab + (wv<<10));
      gAh += BK;
    }
    glds16(gB0, Bb + (wv<<12));
    glds16(gB1, Bb + (wv<<12) + 1024);
    glds16(gB2, Bb + (wv<<12) + 2048);
    glds16(gB3, Bb + (wv<<12) + 3072);
    gB0 += BK; gB1 += BK; gB2 += BK; gB3 += BK;
  };

  auto COMPUTE = [&](const uint8_t* buf){
    const uint8_t* Ab = buf;
    const uint8_t* Bb = buf + ASZ;
#pragma unroll
    for (int kf = 0; kf < 2; ++kf){
      s16x8 a0, a1, b0, b1;
      if constexpr (!ABF){
        a0 = cvt8(*(const f32x4*)(Ab + aoff[0][kf][0]), *(const f32x4*)(Ab + aoff[0][kf][1]));
        a1 = cvt8(*(const f32x4*)(Ab + aoff[1][kf][0]), *(const f32x4*)(Ab + aoff[1][kf][1]));
      } else {
        a0 = *(const s16x8*)(Ab + aoff[0][kf][0]);
        a1 = *(const s16x8*)(Ab + aoff[1][kf][0]);
      }
      b0 = *(const s16x8*)(Bb + boff[0][kf]);
      b1 = *(const s16x8*)(Bb + boff[1][kf]);
      acc[0][0] = __builtin_amdgcn_mfma_f32_16x16x32_bf16(a0, b0, acc[0][0], 0, 0, 0);
      acc[0][1] = __builtin_amdgcn_mfma_f32_16x16x32_bf16(a0, b1, acc[0][1], 0, 0, 0);
      acc[1][0] = __builtin_amdgcn_mfma_f32_16x16x32_bf16(a1, b0, acc[1][0], 0, 0, 0);
      acc[1][1] = __builtin_amdgcn_mfma_f32_16x16x32_bf16(a1, b1, acc[1][1], 0, 0, 0);
    }
  };

  const int ns = K >> 6;
  uint8_t* const lend = lds + NBUF*TSZ;
  uint8_t* bs = lds;
  uint8_t* bc = lds;
  for (int s = 0; s < PRE && s < ns; ++s){
    STAGE(bs);
    bs += TSZ; if (bs == lend) bs = lds;
  }
  for (int t = 0; t < ns; ++t){
    if (t < ns - 1) waitvm<NL>(); else waitvm<0>();
    __builtin_amdgcn_s_barrier();
    asm volatile("" ::: "memory");
    if (t + PRE < ns){
      STAGE(bs);
      bs += TSZ; if (bs == lend) bs = lds;
    }
    COMPUTE(bc);
    bc += TSZ; if (bc == lend) bc = lds;
    asm volatile("" ::: "memory");
  }

  const int mbase = m0 + (g4<<2);
  const int nc0   = (wv<<5) + la;
#pragma unroll
  for (int mi = 0; mi < 2; ++mi){
#pragma unroll
    for (int ni = 0; ni < 2; ++ni){
      s16x4 pk;
#pragma unroll
      for (int r = 0; r < 4; ++r) pk[r] = bf1(acc[mi][ni][r]);
      *(s16x4*)((short*)Outp + (size_t)(nc0 + (ni<<4))*M + (mbase + (mi<<4))) = pk;
    }
  }
}

// ============================================================================
// Reduce kernels: combine 4 K-quarter partials P[4][M][128] (f32).
// ============================================================================

__global__ __launch_bounds__(256) void red_t(
    const float* __restrict__ Pp, const float* __restrict__ fp,
    short* __restrict__ out, int M)
{
  __shared__ short t[128*65];
  const size_t S = (size_t)M*128;
  const int m0 = blockIdx.x * 64;
  const int tid = threadIdx.x;
#pragma unroll
  for (int it = 0; it < 8; ++it){
    const int idx = it*256 + tid;
    const int m = idx >> 5, nq = idx & 31;
    const float* base = Pp + (size_t)(m0+m)*128;
    f32x4 a = ((const f32x4*)(base      ))[nq];
    f32x4 b = ((const f32x4*)(base +   S))[nq];
    f32x4 c = ((const f32x4*)(base + 2*S))[nq];
    f32x4 d = ((const f32x4*)(base + 3*S))[nq];
    const float fv = fp[m0+m];
#pragma unroll
    for (int j = 0; j < 4; ++j)
      t[(nq*4+j)*65 + m] = bf1(fv * ((a[j] + b[j]) + (c[j] + d[j])));
  }
  __syncthreads();
#pragma unroll
  for (int it = 0; it < 8; ++it){
    const int idx = it*256 + tid;
    const int n = idx >> 4, mc = idx & 15;
    s16x4 v;
#pragma unroll
    for (int j = 0; j < 4; ++j) v[j] = t[n*65 + mc*4 + j];
    *(s16x4*)(out + (size_t)n*M + m0 + mc*4) = v;
  }
}

__global__ __launch_bounds__(256) void red_r(
    const float* __restrict__ Pp, short* __restrict__ out, int M)
{
  const size_t S = (size_t)M*128;
  const size_t i0 = (size_t)(blockIdx.x*256 + threadIdx.x) * 8;
  s16x8 v;
#pragma unroll
  for (int h = 0; h < 2; ++h){
    f32x4 a = *(const f32x4*)(Pp + i0 + 4*h);
    f32x4 b = *(const f32x4*)(Pp + i0 + 4*h + S);
    f32x4 c = *(const f32x4*)(Pp + i0 + 4*h + 2*S);
    f32x4 d = *(const f32x4*)(Pp + i0 + 4*h + 3*S);
#pragma unroll
    for (int j = 0; j < 4; ++j)
      v[4*h+j] = bf1(fmaxf((a[j] + b[j]) + (c[j] + d[j]), 0.0f));
  }
  *(s16x8*)(out + i0) = v;
}

__global__ __launch_bounds__(256) void red_f(
    const float* __restrict__ Pp, float* __restrict__ out, int M)
{
  const size_t S = (size_t)M*128;
  const size_t i0 = (size_t)(blockIdx.x*256 + threadIdx.x) * 4;
  f32x4 a = *(const f32x4*)(Pp + i0);
  f32x4 b = *(const f32x4*)(Pp + i0 + S);
  f32x4 c = *(const f32x4*)(Pp + i0 + 2*S);
  f32x4 d = *(const f32x4*)(Pp + i0 + 3*S);
  *(f32x4*)(out + i0) = (a + b) + (c + d);
}

// W1T[n][k] = bf16(W1[k][n]), same for W2 — tiny one-shot transpose.
__global__ void wtrans_k(const float* __restrict__ W1, const float* __restrict__ W2,
                         short* __restrict__ T1, short* __restrict__ T2){
  const int idx = blockIdx.x*256 + threadIdx.x;
  const int m = idx >> 14, rem = idx & 16383;
  const int n = rem >> 7, k = rem & 127;
  const float* W = m ? W2 : W1;
  short* T = m ? T2 : T1;
  T[n*128 + k] = bf1(W[k*128 + n]);
}

extern "C" void kernel_launch(void* const* d_in, const int* in_sizes, int n_in,
                              void* d_out, int out_size, void* d_ws, size_t ws_size,
                              hipStream_t stream){
  const float* input = (const float*)d_in[0];
  const float* wav   = (const float*)d_in[1];
  const float* winv  = (const float*)d_in[2];
  const float* W1    = (const float*)d_in[3];
  const float* f1    = (const float*)d_in[4];
  const float* W2    = (const float*)d_in[5];
  const float* f2    = (const float*)d_in[6];

  constexpr int M = 8192;
  uint8_t* ws = (uint8_t*)d_ws;
  short* W1T = (short*)(ws);                        // 32 KB  [n][k]
  short* W2T = (short*)(ws + (32<<10));             // 32 KB  [n][k]
  short* XWT = (short*)(ws + (64<<10));             // 2 MB   [128][M] bf16
  short* SPT = (short*)(ws + (64<<10) + (2<<20));   // 2 MB   [128][M] bf16
  short* H1  = (short*)(ws + (64<<10) + (4<<20));   // 2 MB   [M][128] bf16
  float* P   = (float*)(ws + (64<<10) + (6<<20));   // 16 MB  f32 [4][M][128]

  dim3 b(256);
  dim3 gbig(M/128, 4);       // 64 x 4 = 256 blocks, 1/CU
  dim3 gns(M/32);            // small K=128 GEMM
  dim3 grt(M/64);            // red_t
  dim3 grr(M*128/(256*8));   // red_r
  dim3 grf(M*128/(256*4));   // red_f
  dim3 gt(128);

  wtrans_k<<<gt, b, 0, stream>>>(W1, W2, W1T, W2T);
  // layer 1
  sgemm<false><<<gns, b, 0, stream>>>(input, W1T, XWT, 128, M);
  gemm_big<<<gbig, b, 0, stream>>>(winv, XWT, P, M, M);
  red_t  <<<grt, b, 0, stream>>>(P, f1, SPT, M);
  gemm_big<<<gbig, b, 0, stream>>>(wav, SPT, P, M, M);
  red_r  <<<grr, b, 0, stream>>>(P, H1, M);
  // layer 2
  sgemm<true ><<<gns, b, 0, stream>>>(H1, W2T, XWT, 128, M);
  gemm_big<<<gbig, b, 0, stream>>>(winv, XWT, P, M, M);
  red_t  <<<grt, b, 0, stream>>>(P, f2, SPT, M);
  gemm_big<<<gbig, b, 0, stream>>>(wav, SPT, P, M, M);
  red_f  <<<grf, b, 0, stream>>>(P, (float*)d_out, M);
}